// Round 11
// baseline (322.850 us; speedup 1.0000x reference)
//
#include <hip/hip_runtime.h>
#include <hip/hip_cooperative_groups.h>

namespace cg = cooperative_groups;

// HMM count-accumulation, counting-sort design, single cooperative kernel.
// out = [trans_count 65*65=4225 | emit_count 500000*64=32M] floats.
//
// Ladder: R1/R2 scattered global atomics wall (~30G txn/s, occupancy-blind);
// R5 scattered u16 stores same wall; R6 counting-sort removes both (no global
// atomics at all now); R7 wave-shuffle scan (254.5); R8 column dir reads
// regressed (REVERTED); R9/R10 dir-plumbing tweaks neutral -- the dir arrays
// were never the cost. R11: fuse phase1+phase2 with one grid.sync so the
// kernel is top-5 visible (counters for attribution), save one launch
// boundary, b128 keybuf reads in the sort scatter pass.

constexpr int N_WORDS  = 500000;
constexpr int N_LABELS = 64;
constexpr int SEQ_LEN  = 512;
constexpr int BINS     = (N_LABELS + 1) * (N_LABELS + 1);   // 4225
constexpr int N_CELLS  = N_WORDS * N_LABELS;                // 32,000,000
constexpr int P        = 1000;     // emit partitions; P*CPP == N_CELLS exactly
constexpr int CPP      = 32000;    // cells/partition; u16 counts = 64,000 B LDS
constexpr int TILE_TOK = 8192;     // tokens per sort tile
constexpr int QPT      = TILE_TOK / 4;   // 2048 quads/tile
constexpr int B        = 1024;
constexpr int MAXG     = 512;
constexpr int MAXTILES = 1024;     // dcol capacity; full-size ntiles = 512
constexpr int FIN_BLOCKS = 5;      // 5*1024 >= 4225 trans bins

// Dynamic-LDS overlay (u32 words):
//  phase A: keybuf[8192] | trans[4225] | cnt[1024] | wsum[16] | sorted(u16 8192)
//  phase B: hist[16000] | dcol[1024]
constexpr int KEYBUF_OFF = 0;
constexpr int TRANS_OFF  = 8192;
constexpr int CNT_OFF    = TRANS_OFF + BINS;       // 12417
constexpr int WSUM_OFF   = CNT_OFF + 1024;         // 13441
constexpr int SORT_OFF   = WSUM_OFF + 16;          // 13457
constexpr int DYN_U32    = SORT_OFF + TILE_TOK/2;  // 17553 (70,212 B)
constexpr int DCOL_OFF   = CPP / 2;                // 16000
static_assert(DYN_U32 >= DCOL_OFF + MAXTILES, "overlay too small");
constexpr size_t DYN_BYTES = (size_t)DYN_U32 * 4;  // 2 blocks/CU (140.4KB <= 160KB)

// ---------------- device bodies (shared by fused + fallback wrappers) -------

__device__ __forceinline__ void tile_sort(const int* __restrict__ words,
                                          const int* __restrict__ labels,
                                          unsigned* __restrict__ dir,
                                          unsigned short* __restrict__ keys,
                                          unsigned* dyn, int tile, int nquads) {
    const int tid = threadIdx.x, lane = tid & 63;
    unsigned* keybuf = dyn + KEYBUF_OFF;
    unsigned* trans  = dyn + TRANS_OFF;
    unsigned* cnt    = dyn + CNT_OFF;
    unsigned* wsum   = dyn + WSUM_OFF;
    unsigned short* sorted = (unsigned short*)(dyn + SORT_OFF);

    const int q0 = tile * QPT;
    const int tq = min(QPT, nquads - q0);
    cnt[tid] = 0u;
    __syncthreads();

    // pass A: keys -> LDS, partition counts, trans hist (two quads/thread)
    for (int lq = tid; lq < tq; lq += B) {
        const int q = q0 + lq;
        const int i = q << 2;
        const int4 w4 = reinterpret_cast<const int4*>(words)[q];
        const int4 l4 = reinterpret_cast<const int4*>(labels)[q];
        const int j0 = i & (SEQ_LEN - 1);
        int pre = (j0 == 0) ? N_LABELS : labels[i - 1];
        int wv[4] = {w4.x, w4.y, w4.z, w4.w};
        int lv[4] = {l4.x, l4.y, l4.z, l4.w};
        unsigned pk[4];
        #pragma unroll
        for (int k = 0; k < 4; ++k) {
            const int lab = lv[k];
            unsigned pack = 0xFFFFFFFFu;
            if (wv[k] != 0) {
                atomicAdd(&trans[lab * (N_LABELS + 1) + pre], 1u);
                const int w = (wv[k] >= N_WORDS) ? 1 : wv[k];
                const unsigned key = (unsigned)w * N_LABELS + (unsigned)lab;
                const unsigned p   = key / CPP;        // magic-mul const div
                pack = (p << 16) | (key - p * CPP);    // loc < 32000 fits u16
                atomicAdd(&cnt[p], 1u);
            }
            pk[k] = pack;
            pre = lab;
        }
        reinterpret_cast<uint4*>(keybuf)[lq] = make_uint4(pk[0], pk[1], pk[2], pk[3]);
    }
    __syncthreads();

    // hierarchical scan of cnt[1024]: wave shfl + wave-sum scan, 2 barriers
    {
        const unsigned c = cnt[tid];
        unsigned v = c;
        #pragma unroll
        for (int d = 1; d < 64; d <<= 1) {
            const unsigned u = __shfl_up(v, d, 64);
            if (lane >= d) v += u;
        }
        if (lane == 63) wsum[tid >> 6] = v;
        __syncthreads();
        if (tid < 16) {
            const unsigned s = wsum[tid];
            unsigned vv = s;
            #pragma unroll
            for (int d = 1; d < 16; d <<= 1) {
                const unsigned u = __shfl_up(vv, d, 64);
                if (tid >= d) vv += u;
            }
            wsum[tid] = vv - s;                  // exclusive wave prefix
        }
        __syncthreads();
        const unsigned off = v - c + wsum[tid >> 6];   // exclusive offset
        cnt[tid] = off;                                 // reuse as scatter cursor
        if (tid < P) dir[(size_t)tile * P + tid] = (c << 16) | off;   // coalesced
    }
    __syncthreads();

    // pass B: LDS scatter into sorted order (b128 keybuf reads, 4 keys/iter)
    for (int t4 = tid; t4 < tq; t4 += B) {
        const uint4 pk4 = reinterpret_cast<const uint4*>(keybuf)[t4];
        unsigned pks[4] = {pk4.x, pk4.y, pk4.z, pk4.w};
        #pragma unroll
        for (int k = 0; k < 4; ++k) {
            const unsigned pack = pks[k];
            if (pack != 0xFFFFFFFFu) {
                const unsigned s = atomicAdd(&cnt[pack >> 16], 1u);
                sorted[s] = (unsigned short)(pack & 0xFFFFu);
            }
        }
    }
    __syncthreads();

    // coalesced write of the sorted tile (16 KB contiguous; garbage tail ok)
    reinterpret_cast<uint4*>(keys + (size_t)tile * TILE_TOK)[tid] =
        reinterpret_cast<const uint4*>(sorted)[tid];
    __syncthreads();
}

__device__ __forceinline__ void part_build(const unsigned* __restrict__ dir,
                                           const unsigned short* __restrict__ keys,
                                           float* __restrict__ out,
                                           unsigned* dyn, int p, int ntiles) {
    unsigned* h    = dyn;                 // 16000 u32 packed u16 counts
    unsigned* dcol = dyn + DCOL_OFF;      // dir column cache
    const int tid = threadIdx.x;

    // cooperative parallel preload of dir column p (L3-resident; R8 showed
    // per-thread INTERLEAVED column reads serialize -- this is one round)
    for (int t = tid; t < ntiles; t += B)
        dcol[t] = dir[(size_t)t * P + p];
    for (int j = tid; j < CPP / 8; j += B)                 // 64KB zero, b128
        reinterpret_cast<uint4*>(h)[j] = make_uint4(0u, 0u, 0u, 0u);
    __syncthreads();

    // gather: two threads per segment (avg segment ~6 keys)
    const int nseg = ntiles << 1;
    for (int s = tid; s < nseg; s += B) {
        const int t = s >> 1, half = s & 1;
        const unsigned e = dcol[t];
        const unsigned c = e >> 16;
        const unsigned mid = (c + 1u) >> 1;
        const unsigned i0 = half ? mid : 0u;
        const unsigned i1 = half ? c : mid;
        const unsigned short* kp = keys + (size_t)t * TILE_TOK + (e & 0xFFFFu);
        for (unsigned i = i0; i < i1; ++i) {
            const unsigned loc = kp[i];
            atomicAdd(&h[loc >> 1], (loc & 1u) ? 65536u : 1u);
        }
    }
    __syncthreads();

    // write sweep; emit + p*CPP is ==4 (mod 16) aligned (proven exact R5-R10)
    float* __restrict__ emit = out + BINS;
    float* dst = emit + (size_t)p * CPP;
    if (tid < 3)
        dst[tid] = (float)((h[tid >> 1] >> ((tid & 1u) * 16)) & 0xFFFFu);
    if (tid == 3)
        dst[CPP - 1] = (float)(h[(CPP - 1) >> 1] >> 16);
    float4* dst4 = reinterpret_cast<float4*>(dst + 3);
    for (int u = tid; u < (CPP - 4) / 4; u += B) {         // 7999 float4s
        const unsigned w0 = h[2 * u + 1];
        const unsigned w1 = h[2 * u + 2];
        const unsigned w2 = h[2 * u + 3];
        float4 f;
        f.x = (float)(w0 >> 16);
        f.y = (float)(w1 & 0xFFFFu);
        f.z = (float)(w1 >> 16);
        f.w = (float)(w2 & 0xFFFFu);
        dst4[u] = f;
    }
}

// ---------------- fused cooperative kernel ----------------

__global__ __launch_bounds__(B)
void fused(const int* __restrict__ words, const int* __restrict__ labels,
           unsigned* __restrict__ dir, unsigned short* __restrict__ keys,
           unsigned* __restrict__ part_t, float* __restrict__ out,
           int n, int ntiles) {
    extern __shared__ unsigned dyn[];
    cg::grid_group grid = cg::this_grid();
    const int tid = threadIdx.x, bid = blockIdx.x, G = gridDim.x;

    unsigned* trans = dyn + TRANS_OFF;
    for (int k = tid; k < BINS; k += B) trans[k] = 0u;

    const int nquads = n >> 2;
    for (int tile = bid; tile < ntiles; tile += G)
        tile_sort(words, labels, dir, keys, dyn, tile, nquads);

    {   // flush trans partial with plain coalesced stores
        unsigned* my = part_t + (size_t)bid * BINS;
        for (int k = tid; k < BINS; k += B) my[k] = trans[k];
    }
    grid.sync();

    // phase B: persistent blocks over 1005 work items (5 finalize + 1000 parts)
    const int W = P + FIN_BLOCKS;
    for (int w = bid; w < W; w += G) {
        __syncthreads();                       // protect dyn overlay reuse
        if (w < FIN_BLOCKS) {                  // trans finalize chunk
            const int k = w * B + tid;
            if (k < BINS) {
                unsigned s = 0;
                for (int pb = 0; pb < G; ++pb) s += part_t[(size_t)pb * BINS + k];
                out[k] = (float)s;
            }
            continue;
        }
        part_build(dir, keys, out, dyn, w - FIN_BLOCKS, ntiles);
    }
}

// ---------------- non-coop fallback wrappers (proven R10 path) --------------

__global__ __launch_bounds__(B)
void phase1_k(const int* __restrict__ words, const int* __restrict__ labels,
              unsigned* __restrict__ dir, unsigned short* __restrict__ keys,
              unsigned* __restrict__ part_t, int n, int ntiles) {
    extern __shared__ unsigned dyn[];
    const int tid = threadIdx.x;
    unsigned* trans = dyn + TRANS_OFF;
    for (int k = tid; k < BINS; k += B) trans[k] = 0u;
    const int nquads = n >> 2;
    for (int tile = blockIdx.x; tile < ntiles; tile += gridDim.x)
        tile_sort(words, labels, dir, keys, dyn, tile, nquads);
    unsigned* my = part_t + (size_t)blockIdx.x * BINS;
    for (int k = tid; k < BINS; k += B) my[k] = trans[k];
}

__global__ __launch_bounds__(B)
void phase2_k(const unsigned* __restrict__ dir,
              const unsigned short* __restrict__ keys,
              const unsigned* __restrict__ part_t,
              float* __restrict__ out, int ntiles, int g1) {
    extern __shared__ unsigned dyn[];
    const unsigned bid = blockIdx.x;
    if (bid < (unsigned)FIN_BLOCKS) {
        const int k = bid * B + threadIdx.x;
        if (k < BINS) {
            unsigned s = 0;
            for (int pb = 0; pb < g1; ++pb) s += part_t[(size_t)pb * BINS + k];
            out[k] = (float)s;
        }
        return;
    }
    part_build(dir, keys, out, dyn, bid - FIN_BLOCKS, ntiles);
}

// ---------------- ultimate fallback (tiny ws) ----------------

__global__ __launch_bounds__(256)
void zero_kernel(uint4* __restrict__ out, int out_quads, int out_size) {
    const uint4 z = {0u, 0u, 0u, 0u};
    const int stride = gridDim.x * blockDim.x;
    for (int q = blockIdx.x * blockDim.x + threadIdx.x; q < out_quads; q += stride)
        out[q] = z;
    if (blockIdx.x == 0 && threadIdx.x < (out_size & 3))
        ((unsigned*)out)[(out_quads << 2) + threadIdx.x] = 0u;
}

__global__ __launch_bounds__(1024)
void count_fallback(const int* __restrict__ words, const int* __restrict__ labels,
                    float* __restrict__ out, int nquads) {
    __shared__ unsigned hist[BINS];
    for (int k = threadIdx.x; k < BINS; k += 1024) hist[k] = 0u;
    __syncthreads();
    float* __restrict__ emit = out + BINS;
    const int stride = gridDim.x * blockDim.x;
    for (int q = blockIdx.x * blockDim.x + threadIdx.x; q < nquads; q += stride) {
        const int i = q << 2;
        const int4 w4 = reinterpret_cast<const int4*>(words)[q];
        const int4 l4 = reinterpret_cast<const int4*>(labels)[q];
        const int j0 = i & (SEQ_LEN - 1);
        int pre = (j0 == 0) ? N_LABELS : labels[i - 1];
        int wv[4] = {w4.x, w4.y, w4.z, w4.w};
        int lv[4] = {l4.x, l4.y, l4.z, l4.w};
        #pragma unroll
        for (int k = 0; k < 4; ++k) {
            const int w = wv[k], lab = lv[k];
            if (w != 0) {
                atomicAdd(&hist[lab * (N_LABELS + 1) + pre], 1u);
                const int we = (w >= N_WORDS) ? 1 : w;
                atomicAdd(&emit[(size_t)we * N_LABELS + lab], 1.0f);
            }
            pre = lab;
        }
    }
    __syncthreads();
    for (int k = threadIdx.x; k < BINS; k += 1024) {
        const unsigned c = hist[k];
        if (c) atomicAdd(&out[k], (float)c);
    }
}

// ---------------- launch ----------------

extern "C" void kernel_launch(void* const* d_in, const int* in_sizes, int n_in,
                              void* d_out, int out_size, void* d_ws, size_t ws_size,
                              hipStream_t stream) {
    const int* words  = (const int*)d_in[0];
    const int* labels = (const int*)d_in[1];
    float* out = (float*)d_out;
    const int n = in_sizes[0];

    const int nquads = n >> 2;
    const int ntiles = (nquads + QPT - 1) / QPT;            // 512 at full size

    // ws: dir | keys | part_t
    const size_t dir_bytes  = (size_t)ntiles * P * sizeof(unsigned);
    const size_t key_bytes  = (size_t)ntiles * TILE_TOK * sizeof(unsigned short);
    const size_t part_bytes = (size_t)MAXG * BINS * sizeof(unsigned);
    const size_t dir_off  = 0;
    const size_t key_off  = dir_off + ((dir_bytes + 255) & ~size_t(255));
    const size_t part_off = key_off + ((key_bytes + 255) & ~size_t(255));
    const size_t need     = part_off + part_bytes;

    // One-time grid sizing (first call is the correctness call, pre-capture).
    static int G = 0;
    if (G == 0) {
        int nb = 0;
        if (hipOccupancyMaxActiveBlocksPerMultiprocessor(
                &nb, (const void*)fused, B, DYN_BYTES) != hipSuccess || nb < 1)
            nb = 1;
        int dev = 0; hipGetDevice(&dev);
        hipDeviceProp_t prop;
        int cus = (hipGetDeviceProperties(&prop, dev) == hipSuccess)
                      ? prop.multiProcessorCount : 256;
        int g = nb * cus;
        G = g < 1 ? 1 : (g > MAXG ? MAXG : g);
    }

    if (ws_size >= need && ntiles <= MAXTILES) {
        unsigned*       dir    = (unsigned*)((char*)d_ws + dir_off);
        unsigned short* keys   = (unsigned short*)((char*)d_ws + key_off);
        unsigned*       part_t = (unsigned*)((char*)d_ws + part_off);

        void* args[] = {(void*)&words, (void*)&labels, (void*)&dir,
                        (void*)&keys, (void*)&part_t, (void*)&out,
                        (void*)&n, (void*)&ntiles};
        const bool ok = (hipLaunchCooperativeKernel(
            (const void*)fused, dim3(G), dim3(B), args, DYN_BYTES, stream)
            == hipSuccess);
        if (!ok) {   // proven R10 two-kernel path
            const int g1 = MAXG;
            phase1_k<<<g1, B, DYN_BYTES, stream>>>(words, labels, dir, keys,
                                                   part_t, n, ntiles);
            phase2_k<<<P + FIN_BLOCKS, B, DYN_BYTES, stream>>>(dir, keys, part_t,
                                                               out, ntiles, g1);
        }
    } else {
        const int out_quads = out_size >> 2;
        zero_kernel<<<2048, 256, 0, stream>>>((uint4*)d_out, out_quads, out_size);
        count_fallback<<<512, 1024, 0, stream>>>(words, labels, out, nquads);
    }
}

// Round 13
// 299.579 us; speedup vs baseline: 1.0777x; 1.0777x over previous
//
#include <hip/hip_runtime.h>
#include <hip/hip_bf16.h>

// HMM count-accumulation with NO scattered global writes.
// out = [trans_count 65*65=4225 | emit_count 500000*64=32M] floats.
//
// Ladder: R1/R2 scattered global atomics wall (~30G txn/s, occupancy-blind);
// R5 scattered u16 stores same wall; R6 counting-sort removes both; R7 wave
// scan (254.5); R8 dir column reads regressed (REVERTED); R9/R10 plumbing
// neutral; R11 coop fusion regressed (+70us for grid.sync/persistent blocks)
// but proved via counters: no pipe saturated (HBM 15%, VALU 5%, conflicts
// ~3us/CU), traffic as designed -> latency/round-trip bound. R12/R13:
// two-kernel again, phase2 at P=2000/CPP=16000, B2=512 -> 4 blocks/CU (2x
// MLP), halved per-block serial work + tail; non-temporal emit stores
// (native ext_vector type -- HIP float4 class is rejected by the builtin).

constexpr int N_WORDS  = 500000;
constexpr int N_LABELS = 64;
constexpr int SEQ_LEN  = 512;
constexpr int BINS     = (N_LABELS + 1) * (N_LABELS + 1);   // 4225
constexpr int N_CELLS  = N_WORDS * N_LABELS;                // 32,000,000
constexpr int P        = 2000;     // emit partitions; P*CPP == N_CELLS exactly
constexpr int CPP      = 16000;    // cells/partition; u16 counts = 32,000 B LDS
constexpr int TILE_TOK = 8192;     // tokens per sort tile
constexpr int QPT      = TILE_TOK / 4;   // 2048 quads/tile
constexpr int B1 = 1024, G1MAX = 512;
constexpr int B2 = 512;            // 8 waves; 4 blocks/CU
constexpr int MAXTILES = 1024;     // dcol capacity; full-size ntiles = 512
constexpr int FIN_BLOCKS = 9;      // 9*512 >= 4225 trans bins
// phase2 dynamic LDS: hist 8000 u32 + dcol 1024 u32 = 36,096 B -> 4 blocks/CU
constexpr size_t DYN2 = (size_t)(CPP / 2 + MAXTILES) * sizeof(unsigned);

typedef float floatx4 __attribute__((ext_vector_type(4)));  // native vec for NT store

// ---------------- phase 1: tile counting sort + trans hist ----------------

__global__ __launch_bounds__(B1)
void phase1(const int* __restrict__ words, const int* __restrict__ labels,
            unsigned* __restrict__ dir,            // [ntiles][P]  (cnt<<16)|off
            unsigned short* __restrict__ keys,     // [ntiles][TILE_TOK] sorted loc
            unsigned* __restrict__ part_t,         // [g1][BINS] trans partials
            int n, int ntiles) {
    __shared__ unsigned trans[BINS];               // 16.9 KB
    __shared__ unsigned keybuf[TILE_TOK];          // 32 KB  (p<<16)|loc, ~0u = pad
    __shared__ unsigned short sorted[TILE_TOK];    // 16 KB
    __shared__ unsigned cnt[2048];                 // 8 KB; reused as scatter cursor
    __shared__ unsigned wsum[16];
    const int tid  = threadIdx.x;
    const int lane = tid & 63;
    const int wid  = tid >> 6;
    for (int k = tid; k < BINS; k += B1) trans[k] = 0u;

    const int nquads = n >> 2;
    for (int tile = blockIdx.x; tile < ntiles; tile += gridDim.x) {
        const int q0 = tile * QPT;
        const int tq = min(QPT, nquads - q0);
        cnt[tid] = 0u; cnt[tid + 1024] = 0u;
        __syncthreads();

        // pass A: keys -> LDS, partition counts, trans hist (two quads/thread)
        for (int lq = tid; lq < tq; lq += B1) {
            const int q = q0 + lq;
            const int i = q << 2;
            const int4 w4 = reinterpret_cast<const int4*>(words)[q];
            const int4 l4 = reinterpret_cast<const int4*>(labels)[q];
            const int j0 = i & (SEQ_LEN - 1);
            int pre = (j0 == 0) ? N_LABELS : labels[i - 1];
            int wv[4] = {w4.x, w4.y, w4.z, w4.w};
            int lv[4] = {l4.x, l4.y, l4.z, l4.w};
            unsigned pk[4];
            #pragma unroll
            for (int k = 0; k < 4; ++k) {
                const int lab = lv[k];
                unsigned pack = 0xFFFFFFFFu;
                if (wv[k] != 0) {
                    atomicAdd(&trans[lab * (N_LABELS + 1) + pre], 1u);
                    const int w = (wv[k] >= N_WORDS) ? 1 : wv[k];
                    const unsigned key = (unsigned)w * N_LABELS + (unsigned)lab;
                    const unsigned p   = key / CPP;        // magic-mul const div
                    pack = (p << 16) | (key - p * CPP);    // loc < 16000 fits u16
                    atomicAdd(&cnt[p], 1u);
                }
                pk[k] = pack;
                pre = lab;
            }
            reinterpret_cast<uint4*>(keybuf)[lq] = make_uint4(pk[0], pk[1], pk[2], pk[3]);
        }
        __syncthreads();

        // pair-wise hierarchical scan of cnt[2048], 2 barriers (R7/R8-proven)
        {
            const unsigned c0 = cnt[2 * tid], c1 = cnt[2 * tid + 1];
            const unsigned s  = c0 + c1;
            unsigned v = s;
            #pragma unroll
            for (int d = 1; d < 64; d <<= 1) {
                const unsigned u = __shfl_up(v, d, 64);
                if (lane >= d) v += u;
            }
            if (lane == 63) wsum[wid] = v;
            __syncthreads();
            if (tid < 16) {
                const unsigned sv = wsum[tid];
                unsigned vv = sv;
                #pragma unroll
                for (int d = 1; d < 16; d <<= 1) {
                    const unsigned u = __shfl_up(vv, d, 64);
                    if (tid >= d) vv += u;
                }
                wsum[tid] = vv - sv;               // exclusive wave prefix
            }
            __syncthreads();
            const unsigned ex = v - s + wsum[wid]; // exclusive offset of cell 2*tid
            cnt[2 * tid]     = ex;                 // reuse as scatter cursor
            cnt[2 * tid + 1] = ex + c0;
            if (2 * tid + 1 < P)                   // threads 0..999: uint2 dir write
                reinterpret_cast<uint2*>(dir + (size_t)tile * P)[tid] =
                    make_uint2((c0 << 16) | ex, (c1 << 16) | (ex + c0));
        }
        __syncthreads();

        // pass B: LDS scatter into sorted order (b128 keybuf reads)
        for (int t4 = tid; t4 < tq; t4 += B1) {
            const uint4 pk4 = reinterpret_cast<const uint4*>(keybuf)[t4];
            unsigned pks[4] = {pk4.x, pk4.y, pk4.z, pk4.w};
            #pragma unroll
            for (int k = 0; k < 4; ++k) {
                const unsigned pack = pks[k];
                if (pack != 0xFFFFFFFFu) {
                    const unsigned s = atomicAdd(&cnt[pack >> 16], 1u);
                    sorted[s] = (unsigned short)(pack & 0xFFFFu);
                }
            }
        }
        __syncthreads();

        // coalesced write of the sorted tile (16 KB contiguous; garbage tail ok)
        reinterpret_cast<uint4*>(keys + (size_t)tile * TILE_TOK)[tid] =
            reinterpret_cast<const uint4*>(sorted)[tid];
        __syncthreads();
    }

    unsigned* my = part_t + (size_t)blockIdx.x * BINS;
    for (int k = tid; k < BINS; k += B1) my[k] = trans[k];  // plain coalesced
}

// ---------------- phase 2: emit slices + fused trans finalize ----------------

__global__ __launch_bounds__(B2)
void phase2(const unsigned* __restrict__ dir,              // [ntiles][P]
            const unsigned short* __restrict__ keys,       // [ntiles][TILE_TOK]
            const unsigned* __restrict__ part_t,
            float* __restrict__ out, int ntiles, int g1) {
    extern __shared__ unsigned h[];                        // [8000 hist | dcol]
    unsigned* dcol = h + CPP / 2;
    const unsigned bid = blockIdx.x;
    const int tid = threadIdx.x;

    if (bid < (unsigned)FIN_BLOCKS) {                      // fused trans finalize
        const int k = bid * B2 + tid;                      // first scheduling round,
        if (k < BINS) {                                    // hides under emit blocks
            unsigned s = 0;
            for (int pb = 0; pb < g1; ++pb) s += part_t[(size_t)pb * BINS + k];
            out[k] = (float)s;
        }
        return;
    }
    const unsigned p = bid - FIN_BLOCKS;                   // partition index

    // cooperative parallel preload of dir column p (independent loads; R8's
    // per-thread interleaved column reads are the pattern to avoid)
    for (int t = tid; t < ntiles; t += B2)
        dcol[t] = dir[(size_t)t * P + p];
    for (int j = tid; j < CPP / 8; j += B2)                // 32KB zero, b128
        reinterpret_cast<uint4*>(h)[j] = make_uint4(0u, 0u, 0u, 0u);
    __syncthreads();

    // gather: one thread per tile-segment (avg ~3.15 keys/segment at P=2000)
    for (int t = tid; t < ntiles; t += B2) {
        const unsigned e = dcol[t];
        const unsigned c = e >> 16;
        const unsigned short* kp = keys + (size_t)t * TILE_TOK + (e & 0xFFFFu);
        for (unsigned i = 0; i < c; ++i) {
            const unsigned loc = kp[i];
            atomicAdd(&h[loc >> 1], (loc & 1u) ? 65536u : 1u);
        }
    }
    __syncthreads();

    // write sweep; emit + p*CPP is ==4 (mod 16) aligned (16900 + p*64000 B)
    float* __restrict__ emit = out + BINS;
    float* dst = emit + (size_t)p * CPP;
    if (tid < 3)
        dst[tid] = (float)((h[tid >> 1] >> ((tid & 1u) * 16)) & 0xFFFFu);
    if (tid == 3)
        dst[CPP - 1] = (float)(h[(CPP - 1) >> 1] >> 16);   // 15999 odd -> hi half
    floatx4* dst4 = reinterpret_cast<floatx4*>(dst + 3);
    for (int u = tid; u < (CPP - 4) / 4; u += B2) {        // 3999 float4s
        const unsigned w0 = h[2 * u + 1];
        const unsigned w1 = h[2 * u + 2];
        const unsigned w2 = h[2 * u + 3];
        floatx4 f;
        f.x = (float)(w0 >> 16);
        f.y = (float)(w1 & 0xFFFFu);
        f.z = (float)(w1 >> 16);
        f.w = (float)(w2 & 0xFFFFu);
        __builtin_nontemporal_store(f, &dst4[u]);          // out never re-read
    }
}

// ---------------- fallback (ws too small / too many tiles) ----------------

__global__ __launch_bounds__(256)
void zero_kernel(uint4* __restrict__ out, int out_quads, int out_size) {
    const uint4 z = {0u, 0u, 0u, 0u};
    const int stride = gridDim.x * blockDim.x;
    for (int q = blockIdx.x * blockDim.x + threadIdx.x; q < out_quads; q += stride)
        out[q] = z;
    if (blockIdx.x == 0 && threadIdx.x < (out_size & 3))
        ((unsigned*)out)[(out_quads << 2) + threadIdx.x] = 0u;
}

__global__ __launch_bounds__(1024)
void count_fallback(const int* __restrict__ words, const int* __restrict__ labels,
                    float* __restrict__ out, int nquads) {
    __shared__ unsigned hist[BINS];
    for (int k = threadIdx.x; k < BINS; k += 1024) hist[k] = 0u;
    __syncthreads();
    float* __restrict__ emit = out + BINS;
    const int stride = gridDim.x * blockDim.x;
    for (int q = blockIdx.x * blockDim.x + threadIdx.x; q < nquads; q += stride) {
        const int i = q << 2;
        const int4 w4 = reinterpret_cast<const int4*>(words)[q];
        const int4 l4 = reinterpret_cast<const int4*>(labels)[q];
        const int j0 = i & (SEQ_LEN - 1);
        int pre = (j0 == 0) ? N_LABELS : labels[i - 1];
        int wv[4] = {w4.x, w4.y, w4.z, w4.w};
        int lv[4] = {l4.x, l4.y, l4.z, l4.w};
        #pragma unroll
        for (int k = 0; k < 4; ++k) {
            const int w = wv[k], lab = lv[k];
            if (w != 0) {
                atomicAdd(&hist[lab * (N_LABELS + 1) + pre], 1u);
                const int we = (w >= N_WORDS) ? 1 : w;
                atomicAdd(&emit[(size_t)we * N_LABELS + lab], 1.0f);
            }
            pre = lab;
        }
    }
    __syncthreads();
    for (int k = threadIdx.x; k < BINS; k += 1024) {
        const unsigned c = hist[k];
        if (c) atomicAdd(&out[k], (float)c);
    }
}

// ---------------- launch ----------------

extern "C" void kernel_launch(void* const* d_in, const int* in_sizes, int n_in,
                              void* d_out, int out_size, void* d_ws, size_t ws_size,
                              hipStream_t stream) {
    const int* words  = (const int*)d_in[0];
    const int* labels = (const int*)d_in[1];
    float* out = (float*)d_out;
    const int n = in_sizes[0];

    const int nquads = n >> 2;
    const int ntiles = (nquads + QPT - 1) / QPT;            // 512 at full size
    const int g1     = ntiles < G1MAX ? ntiles : G1MAX;

    // ws: dir | keys | part_t
    const size_t dir_bytes  = (size_t)ntiles * P * sizeof(unsigned);        // 4 MB
    const size_t key_bytes  = (size_t)ntiles * TILE_TOK * sizeof(unsigned short); // 8 MB
    const size_t part_bytes = (size_t)g1 * BINS * sizeof(unsigned);         // 8.65 MB
    const size_t dir_off  = 0;
    const size_t key_off  = dir_off + ((dir_bytes + 255) & ~size_t(255));
    const size_t part_off = key_off + ((key_bytes + 255) & ~size_t(255));
    const size_t need     = part_off + part_bytes;

    if (ws_size >= need && ntiles <= MAXTILES) {
        unsigned*       dir    = (unsigned*)((char*)d_ws + dir_off);
        unsigned short* keys   = (unsigned short*)((char*)d_ws + key_off);
        unsigned*       part_t = (unsigned*)((char*)d_ws + part_off);

        phase1<<<g1, B1, 0, stream>>>(words, labels, dir, keys, part_t, n, ntiles);
        phase2<<<P + FIN_BLOCKS, B2, DYN2, stream>>>(dir, keys, part_t, out,
                                                     ntiles, g1);
    } else {
        const int out_quads = out_size >> 2;
        zero_kernel<<<2048, 256, 0, stream>>>((uint4*)d_out, out_quads, out_size);
        count_fallback<<<512, 1024, 0, stream>>>(words, labels, out, nquads);
    }
}

// Round 14
// 254.377 us; speedup vs baseline: 1.2692x; 1.1777x over previous
//
#include <hip/hip_runtime.h>
#include <hip/hip_bf16.h>

// HMM count-accumulation with NO scattered global writes.
// out = [trans_count 65*65=4225 | emit_count 500000*64=32M] floats.
//
// Ladder: R1/R2 scattered global atomics wall (~30G txn/s, occupancy-blind);
// R5 scattered u16 stores same wall; R6 counting-sort removes both; R7 wave
// scan (254.5, tied-best); R8 dir column reads +100us (REVERTED); R9/R10
// plumbing neutral (254.3, best); R11 coop fusion +70us (counters: nothing
// saturated -> latency-bound); R13 P=2000 regressed (+45us, phase2 102us,
// FETCH +20MB: segment line-fetches scale with P; P=1000 is the knee).
// R14: exact R10 structure, ONE change -- non-temporal emit stores (output
// is write-once; avoid L2 allocation, keep keys/dir L2-resident for gather).

constexpr int N_WORDS  = 500000;
constexpr int N_LABELS = 64;
constexpr int SEQ_LEN  = 512;
constexpr int BINS     = (N_LABELS + 1) * (N_LABELS + 1);   // 4225
constexpr int N_CELLS  = N_WORDS * N_LABELS;                // 32,000,000
constexpr int P        = 1000;     // emit partitions; P*CPP == N_CELLS exactly
constexpr int CPP      = 32000;    // cells/partition; u16 counts = 64,000 B LDS
constexpr int TILE_TOK = 8192;     // tokens per sort tile
constexpr int QPT      = TILE_TOK / 4;   // 2048 quads/tile
constexpr int B1 = 1024, G1 = 512;
constexpr int B2 = 1024;
constexpr int MAXTILES = 1024;     // dcol capacity; full-size ntiles = 512
constexpr int FIN_BLOCKS = 5;      // 5*1024 >= 4225
// phase2 dynamic LDS: hist 16000 u32 + dcol 1024 u32 = 68,096 B (2 blocks/CU)
constexpr size_t DYN2 = (size_t)(CPP / 2 + MAXTILES) * sizeof(unsigned);

typedef float floatx4 __attribute__((ext_vector_type(4)));  // native vec for NT store

// ---------------- phase 1: tile counting sort + trans hist ----------------

__global__ __launch_bounds__(B1)
void phase1(const int* __restrict__ words, const int* __restrict__ labels,
            unsigned* __restrict__ dir,            // [ntiles][P]  (cnt<<16)|off
            unsigned short* __restrict__ keys,     // [ntiles][TILE_TOK] sorted loc
            unsigned* __restrict__ part_t,         // [G1][BINS] trans partials
            int n, int ntiles) {
    __shared__ unsigned trans[BINS];               // 16.9 KB
    __shared__ unsigned keybuf[TILE_TOK];          // 32 KB  (p<<16)|loc, ~0u = pad
    __shared__ unsigned short sorted[TILE_TOK];    // 16 KB
    __shared__ unsigned cnt[1024];                 // 4 KB; reused as scatter cursor
    __shared__ unsigned wsum[16];
    const int tid  = threadIdx.x;
    const int lane = tid & 63;
    for (int k = tid; k < BINS; k += B1) trans[k] = 0u;

    const int nquads = n >> 2;
    for (int tile = blockIdx.x; tile < ntiles; tile += gridDim.x) {
        const int q0 = tile * QPT;
        const int tq = min(QPT, nquads - q0);
        cnt[tid] = 0u;
        __syncthreads();

        // pass A: keys -> LDS, partition counts, trans hist (two quads/thread)
        for (int lq = tid; lq < tq; lq += B1) {
            const int q = q0 + lq;
            const int i = q << 2;
            const int4 w4 = reinterpret_cast<const int4*>(words)[q];
            const int4 l4 = reinterpret_cast<const int4*>(labels)[q];
            const int j0 = i & (SEQ_LEN - 1);
            int pre = (j0 == 0) ? N_LABELS : labels[i - 1];
            int wv[4] = {w4.x, w4.y, w4.z, w4.w};
            int lv[4] = {l4.x, l4.y, l4.z, l4.w};
            unsigned pk[4];
            #pragma unroll
            for (int k = 0; k < 4; ++k) {
                const int lab = lv[k];
                unsigned pack = 0xFFFFFFFFu;
                if (wv[k] != 0) {
                    atomicAdd(&trans[lab * (N_LABELS + 1) + pre], 1u);
                    const int w = (wv[k] >= N_WORDS) ? 1 : wv[k];
                    const unsigned key = (unsigned)w * N_LABELS + (unsigned)lab;
                    const unsigned p   = key / CPP;        // magic-mul const div
                    pack = (p << 16) | (key - p * CPP);    // loc < 32000 fits u16
                    atomicAdd(&cnt[p], 1u);
                }
                pk[k] = pack;
                pre = lab;
            }
            reinterpret_cast<uint4*>(keybuf)[lq] = make_uint4(pk[0], pk[1], pk[2], pk[3]);
        }
        __syncthreads();

        // hierarchical scan of cnt[1024]: wave shfl + wave-sum scan, 2 barriers
        {
            const unsigned c = cnt[tid];
            unsigned v = c;
            #pragma unroll
            for (int d = 1; d < 64; d <<= 1) {
                const unsigned u = __shfl_up(v, d, 64);
                if (lane >= d) v += u;
            }
            if (lane == 63) wsum[tid >> 6] = v;
            __syncthreads();
            if (tid < 16) {
                const unsigned s = wsum[tid];
                unsigned vv = s;
                #pragma unroll
                for (int d = 1; d < 16; d <<= 1) {
                    const unsigned u = __shfl_up(vv, d, 64);
                    if (tid >= d) vv += u;
                }
                wsum[tid] = vv - s;                 // exclusive wave prefix
            }
            __syncthreads();
            const unsigned off = v - c + wsum[tid >> 6];  // exclusive offset
            cnt[tid] = off;                                // reuse as cursor
            if (tid < P) dir[(size_t)tile * P + tid] = (c << 16) | off;  // coalesced
        }
        __syncthreads();

        // pass B: LDS scatter into sorted order (b128 keybuf reads)
        for (int t4 = tid; t4 < tq; t4 += B1) {
            const uint4 pk4 = reinterpret_cast<const uint4*>(keybuf)[t4];
            unsigned pks[4] = {pk4.x, pk4.y, pk4.z, pk4.w};
            #pragma unroll
            for (int k = 0; k < 4; ++k) {
                const unsigned pack = pks[k];
                if (pack != 0xFFFFFFFFu) {
                    const unsigned s = atomicAdd(&cnt[pack >> 16], 1u);
                    sorted[s] = (unsigned short)(pack & 0xFFFFu);
                }
            }
        }
        __syncthreads();

        // coalesced write of the sorted tile (16 KB contiguous; garbage tail ok)
        reinterpret_cast<uint4*>(keys + (size_t)tile * TILE_TOK)[tid] =
            reinterpret_cast<const uint4*>(sorted)[tid];
        __syncthreads();
    }

    unsigned* my = part_t + (size_t)blockIdx.x * BINS;
    for (int k = tid; k < BINS; k += B1) my[k] = trans[k];  // plain coalesced
}

// ---------------- phase 2: emit slices + fused trans finalize ----------------

__global__ __launch_bounds__(B2)
void phase2(const unsigned* __restrict__ dir,              // [ntiles][P]
            const unsigned short* __restrict__ keys,       // [ntiles][TILE_TOK]
            const unsigned* __restrict__ part_t,
            float* __restrict__ out, int ntiles) {
    extern __shared__ unsigned h[];                        // [16000 hist | 1024 dcol]
    unsigned* dcol = h + CPP / 2;
    const unsigned bid = blockIdx.x;
    const int tid = threadIdx.x;

    if (bid < (unsigned)FIN_BLOCKS) {                      // fused trans finalize
        const int k = bid * B2 + tid;                      // first scheduling round,
        if (k < BINS) {                                    // hides under emit blocks
            unsigned s = 0;
            #pragma unroll 8
            for (int pb = 0; pb < G1; ++pb) s += part_t[(size_t)pb * BINS + k];
            out[k] = (float)s;
        }
        return;
    }
    const unsigned p = bid - FIN_BLOCKS;                   // partition index

    // cooperative parallel preload of dir column p (independent loads)
    for (int t = tid; t < ntiles; t += B2)
        dcol[t] = dir[(size_t)t * P + p];
    for (int j = tid; j < CPP / 8; j += B2)                // 64KB zero, b128
        reinterpret_cast<uint4*>(h)[j] = make_uint4(0u, 0u, 0u, 0u);
    __syncthreads();

    // gather: two threads per segment (avg segment ~6 keys)
    const int nseg = ntiles << 1;
    for (int s = tid; s < nseg; s += B2) {
        const int t = s >> 1, half = s & 1;
        const unsigned e = dcol[t];
        const unsigned c = e >> 16;
        const unsigned mid = (c + 1u) >> 1;
        const unsigned i0 = half ? mid : 0u;
        const unsigned i1 = half ? c : mid;
        const unsigned short* kp = keys + (size_t)t * TILE_TOK + (e & 0xFFFFu);
        for (unsigned i = i0; i < i1; ++i) {
            const unsigned loc = kp[i];
            atomicAdd(&h[loc >> 1], (loc & 1u) ? 65536u : 1u);
        }
    }
    __syncthreads();

    // write sweep; emit + p*CPP is ==4 (mod 16) aligned (proven exact R5-R13).
    // NON-TEMPORAL: output is write-once, never re-read by us -- skip L2
    // allocation so keys/dir stay resident for still-running gather blocks.
    float* __restrict__ emit = out + BINS;
    float* dst = emit + (size_t)p * CPP;
    if (tid < 3)
        dst[tid] = (float)((h[tid >> 1] >> ((tid & 1u) * 16)) & 0xFFFFu);
    if (tid == 3)
        dst[CPP - 1] = (float)(h[(CPP - 1) >> 1] >> 16);
    floatx4* dst4 = reinterpret_cast<floatx4*>(dst + 3);
    for (int u = tid; u < (CPP - 4) / 4; u += B2) {        // 7999 float4s
        const unsigned w0 = h[2 * u + 1];
        const unsigned w1 = h[2 * u + 2];
        const unsigned w2 = h[2 * u + 3];
        floatx4 f;
        f.x = (float)(w0 >> 16);
        f.y = (float)(w1 & 0xFFFFu);
        f.z = (float)(w1 >> 16);
        f.w = (float)(w2 & 0xFFFFu);
        __builtin_nontemporal_store(f, &dst4[u]);
    }
}

// ---------------- fallback (ws too small / too many tiles) ----------------

__global__ __launch_bounds__(256)
void zero_kernel(uint4* __restrict__ out, int out_quads, int out_size) {
    const uint4 z = {0u, 0u, 0u, 0u};
    const int stride = gridDim.x * blockDim.x;
    for (int q = blockIdx.x * blockDim.x + threadIdx.x; q < out_quads; q += stride)
        out[q] = z;
    if (blockIdx.x == 0 && threadIdx.x < (out_size & 3))
        ((unsigned*)out)[(out_quads << 2) + threadIdx.x] = 0u;
}

__global__ __launch_bounds__(1024)
void count_fallback(const int* __restrict__ words, const int* __restrict__ labels,
                    float* __restrict__ out, int nquads) {
    __shared__ unsigned hist[BINS];
    for (int k = threadIdx.x; k < BINS; k += 1024) hist[k] = 0u;
    __syncthreads();
    float* __restrict__ emit = out + BINS;
    const int stride = gridDim.x * blockDim.x;
    for (int q = blockIdx.x * blockDim.x + threadIdx.x; q < nquads; q += stride) {
        const int i = q << 2;
        const int4 w4 = reinterpret_cast<const int4*>(words)[q];
        const int4 l4 = reinterpret_cast<const int4*>(labels)[q];
        const int j0 = i & (SEQ_LEN - 1);
        int pre = (j0 == 0) ? N_LABELS : labels[i - 1];
        int wv[4] = {w4.x, w4.y, w4.z, w4.w};
        int lv[4] = {l4.x, l4.y, l4.z, l4.w};
        #pragma unroll
        for (int k = 0; k < 4; ++k) {
            const int w = wv[k], lab = lv[k];
            if (w != 0) {
                atomicAdd(&hist[lab * (N_LABELS + 1) + pre], 1u);
                const int we = (w >= N_WORDS) ? 1 : w;
                atomicAdd(&emit[(size_t)we * N_LABELS + lab], 1.0f);
            }
            pre = lab;
        }
    }
    __syncthreads();
    for (int k = threadIdx.x; k < BINS; k += 1024) {
        const unsigned c = hist[k];
        if (c) atomicAdd(&out[k], (float)c);
    }
}

// ---------------- launch ----------------

extern "C" void kernel_launch(void* const* d_in, const int* in_sizes, int n_in,
                              void* d_out, int out_size, void* d_ws, size_t ws_size,
                              hipStream_t stream) {
    const int* words  = (const int*)d_in[0];
    const int* labels = (const int*)d_in[1];
    float* out = (float*)d_out;
    const int n = in_sizes[0];

    const int nquads = n >> 2;
    const int ntiles = (nquads + QPT - 1) / QPT;            // 512 at full size

    // ws: dir | keys | part_t
    const size_t dir_bytes  = (size_t)ntiles * P * sizeof(unsigned);
    const size_t key_bytes  = (size_t)ntiles * TILE_TOK * sizeof(unsigned short);
    const size_t part_bytes = (size_t)G1 * BINS * sizeof(unsigned);
    const size_t dir_off  = 0;
    const size_t key_off  = dir_off + ((dir_bytes + 255) & ~size_t(255));
    const size_t part_off = key_off + ((key_bytes + 255) & ~size_t(255));
    const size_t need     = part_off + part_bytes;

    if (ws_size >= need && ntiles <= MAXTILES) {
        unsigned*       dir    = (unsigned*)((char*)d_ws + dir_off);
        unsigned short* keys   = (unsigned short*)((char*)d_ws + key_off);
        unsigned*       part_t = (unsigned*)((char*)d_ws + part_off);

        phase1<<<G1, B1, 0, stream>>>(words, labels, dir, keys, part_t, n, ntiles);
        phase2<<<P + FIN_BLOCKS, B2, DYN2, stream>>>(dir, keys, part_t, out, ntiles);
    } else {
        const int out_quads = out_size >> 2;
        zero_kernel<<<2048, 256, 0, stream>>>((uint4*)d_out, out_quads, out_size);
        count_fallback<<<512, 1024, 0, stream>>>(words, labels, out, nquads);
    }
}